// Round 1
// baseline (2095.991 us; speedup 1.0000x reference)
//
#include <hip/hip_runtime.h>
#include <stdint.h>

#define T_ 2
#define H_ 384
#define W_ 384
#define C_ 128
#define HN_ 48
#define WN_ 48
#define NWIN_ (T_*HN_*WN_)
#define SCALE_ 0.17677669529663687f

// LDS row strides (chosen for 16B alignment + bank-conflict-free b128 reads)
#define XS 129     // xin fp32 row stride (100 rows)   -> 51,600 B (aliased as O)
#define OS 132     // O fp32 row stride (64 rows)
#define TS 136     // tmp bf16 row stride (64 rows)    -> 17,408 B
#define QS 136     // qkv bf16 row stride (3x64 rows)  -> 52,224 B
#define WS 136     // staged weights bf16 (128 rows)   -> 34,816 B

__device__ __forceinline__ float bflo(unsigned int u){ union{unsigned int i;float f;}x; x.i=u<<16; return x.f; }
__device__ __forceinline__ float bfhi(unsigned int u){ union{unsigned int i;float f;}x; x.i=u&0xffff0000u; return x.f; }
__device__ __forceinline__ float2 bf2(unsigned int u){ return make_float2(bflo(u), bfhi(u)); }
__device__ __forceinline__ unsigned short f2bf(float f){
  union{float f;unsigned int i;}x; x.f=f;
  unsigned int r = x.i + 0x7fffu + ((x.i>>16)&1u);   // round-to-nearest-even
  return (unsigned short)(r>>16);
}

union U4 { uint4 v; unsigned int w[4]; };

__global__ __launch_bounds__(512)
void winattn_kernel(const float* __restrict__ vid, const float* __restrict__ rpb,
                    const float* __restrict__ qdw, const float* __restrict__ qdwb,
                    const float* __restrict__ qpw, const float* __restrict__ qpwb,
                    const float* __restrict__ kdw, const float* __restrict__ kdwb,
                    const float* __restrict__ kpw, const float* __restrict__ kpwb,
                    const float* __restrict__ vdw, const float* __restrict__ vdwb,
                    const float* __restrict__ vpw, const float* __restrict__ vpwb,
                    const float* __restrict__ pjw, const float* __restrict__ pjb,
                    float* __restrict__ out)
{
  __shared__ float s_xin[100*XS];            // input halo tile; reused as O[64][OS] fp32
  __shared__ unsigned short s_tmp[64*TS];    // depthwise output, bf16
  __shared__ unsigned short s_qkv[3][64*QS]; // Q(scaled)/K/V, bf16
  __shared__ unsigned short s_wst[128*WS];   // staged 128x128 weights, bf16
  __shared__ float s_rpb[900];               // rel-pos-bias table (225x4)

  const int tid = threadIdx.x;
  const int wid = blockIdx.x;
  const int t  = wid / (HN_*WN_);
  const int hw = wid % (HN_*WN_);
  const int hn = hw / WN_, wn = hw % WN_;
  const int h0 = hn*8, w0 = wn*8;

  // ---- stage input tile (10x10 px, 128ch, zero-padded at image border) + rpb ----
  for (int i = tid; i < 100*32; i += 512) {
    int pp = i >> 5;                 // padded pixel 0..99
    int c4 = (i & 31) << 2;          // channel group of 4
    int hh = h0 - 1 + pp/10, ww = w0 - 1 + pp%10;
    float4 v = make_float4(0.f,0.f,0.f,0.f);
    if ((unsigned)hh < (unsigned)H_ && (unsigned)ww < (unsigned)W_)
      v = *reinterpret_cast<const float4*>(&vid[(((long)t*H_ + hh)*W_ + ww)*C_ + c4]);
    float* dst = &s_xin[pp*XS + c4];
    dst[0]=v.x; dst[1]=v.y; dst[2]=v.z; dst[3]=v.w;
  }
  for (int i = tid; i < 900; i += 512) s_rpb[i] = rpb[i];
  __syncthreads();

  const float* DW[3]  = {qdw, kdw, vdw};
  const float* DWB[3] = {qdwb, kdwb, vdwb};
  const float* PW[3]  = {qpw, kpw, vpw};
  const float* PWB[3] = {qpwb, kpwb, vpwb};

  const int pix = tid >> 3;          // 0..63 (window token)
  const int lb  = tid & 7;           // 0..7  (channel lane group)
  const int py  = pix >> 3, px = pix & 7;

  for (int p = 0; p < 3; ++p) {
    // ---- depthwise 3x3 + bias + relu -> s_tmp (bf16) ----
    {
      const float* dw = DW[p]; const float* db = DWB[p];
      for (int i = 0; i < 16; ++i) {
        int c = lb*16 + i;           // contiguous channels for clean xin banks
        float acc = db[c];
        const float* w9 = &dw[c*9];
        #pragma unroll
        for (int dy = 0; dy < 3; ++dy)
          #pragma unroll
          for (int dx = 0; dx < 3; ++dx)
            acc += s_xin[((py+dy)*10 + (px+dx))*XS + c] * w9[dy*3+dx];
        s_tmp[pix*TS + c] = f2bf(fmaxf(acc, 0.f));
      }
    }
    // ---- stage pointwise weights -> s_wst (bf16) ----
    for (int i = tid; i < 128*32; i += 512) {
      int co = i >> 5, c4 = (i&31) << 2;
      float4 w = *reinterpret_cast<const float4*>(&PW[p][co*128 + c4]);
      unsigned short* d = &s_wst[co*WS + c4];
      d[0]=f2bf(w.x); d[1]=f2bf(w.y); d[2]=f2bf(w.z); d[3]=f2bf(w.w);
    }
    __syncthreads();
    // ---- pointwise 1x1: qkv[p][pix][lb+8i] (fp32 accum) ----
    {
      const float* pb = PWB[p];
      float acc[16];
      #pragma unroll
      for (int i=0;i<16;++i) acc[i] = pb[lb + 8*i];
      const uint4* xr = reinterpret_cast<const uint4*>(&s_tmp[pix*TS]);
      for (int j = 0; j < 16; ++j) {         // 8-channel chunks of ci
        U4 xv; xv.v = xr[j];
        float xf[8];
        #pragma unroll
        for (int q=0;q<4;++q){ float2 f = bf2(xv.w[q]); xf[2*q]=f.x; xf[2*q+1]=f.y; }
        #pragma unroll
        for (int i=0;i<16;++i) {
          U4 wv; wv.v = *reinterpret_cast<const uint4*>(&s_wst[(lb + 8*i)*WS + 8*j]);
          float a = acc[i];
          #pragma unroll
          for (int q=0;q<4;++q){ float2 f = bf2(wv.w[q]); a += xf[2*q]*f.x + xf[2*q+1]*f.y; }
          acc[i] = a;
        }
      }
      const float scl = (p==0) ? SCALE_ : 1.f;
      #pragma unroll
      for (int i=0;i<16;++i)
        s_qkv[p][pix*QS + lb + 8*i] = f2bf(acc[i]*scl);
    }
    __syncthreads();
  }

  // ---- attention (lanes 0..255: one lane per (head,row), online softmax) ----
  // ---- lanes 256..511: stage proj weights into s_wst                     ----
  if (tid < 256) {
    const int he = tid >> 6, n = tid & 63;
    const int yi = n >> 3, xi = n & 7;
    float qv[32];
    const uint4* qr = reinterpret_cast<const uint4*>(&s_qkv[0][n*QS + he*32]);
    #pragma unroll
    for (int j=0;j<4;++j){
      U4 q4; q4.v = qr[j];
      #pragma unroll
      for (int q=0;q<4;++q){ float2 f = bf2(q4.w[q]); qv[8*j+2*q]=f.x; qv[8*j+2*q+1]=f.y; }
    }
    float mx = -1e30f, ssum = 0.f;
    float oa[32];
    #pragma unroll
    for (int d=0;d<32;++d) oa[d]=0.f;
    for (int m = 0; m < 64; ++m) {           // rolled: online softmax, no S[64] array
      float s = s_rpb[((yi-(m>>3)+7)*15 + (xi-(m&7)+7))*4 + he];
      const uint4* kr = reinterpret_cast<const uint4*>(&s_qkv[1][m*QS + he*32]);
      #pragma unroll
      for (int j=0;j<4;++j){
        U4 k4; k4.v = kr[j];
        #pragma unroll
        for (int q=0;q<4;++q){ float2 f = bf2(k4.w[q]); s += qv[8*j+2*q]*f.x + qv[8*j+2*q+1]*f.y; }
      }
      float nm = fmaxf(mx, s);
      float corr = __expf(mx - nm);
      float pmv  = __expf(s - nm);
      mx = nm;
      ssum = ssum*corr + pmv;
      const uint4* vr = reinterpret_cast<const uint4*>(&s_qkv[2][m*QS + he*32]);
      #pragma unroll
      for (int j=0;j<4;++j){
        U4 v4; v4.v = vr[j];
        #pragma unroll
        for (int q=0;q<4;++q){
          float2 f = bf2(v4.w[q]);
          oa[8*j+2*q]   = oa[8*j+2*q]  *corr + pmv*f.x;
          oa[8*j+2*q+1] = oa[8*j+2*q+1]*corr + pmv*f.y;
        }
      }
    }
    float inv = 1.f / ssum;
    float* orow = &s_xin[n*OS + he*32];      // xin region dead -> reuse as O
    #pragma unroll
    for (int d=0;d<32;++d) orow[d] = oa[d]*inv;
  } else {
    for (int i = tid - 256; i < 128*32; i += 256) {
      int co = i >> 5, c4 = (i&31) << 2;
      float4 w = *reinterpret_cast<const float4*>(&pjw[co*128 + c4]);
      unsigned short* d = &s_wst[co*WS + c4];
      d[0]=f2bf(w.x); d[1]=f2bf(w.y); d[2]=f2bf(w.z); d[3]=f2bf(w.w);
    }
  }
  __syncthreads();

  // ---- projection (128x128) + output write ----
  {
    float acc[16];
    #pragma unroll
    for (int i=0;i<16;++i) acc[i] = pjb[lb + 8*i];
    const float4* orow = reinterpret_cast<const float4*>(&s_xin[pix*OS]);
    for (int j = 0; j < 16; ++j) {           // 8-channel chunks of ci
      float4 o0 = orow[2*j], o1 = orow[2*j+1];
      float xf[8] = {o0.x,o0.y,o0.z,o0.w,o1.x,o1.y,o1.z,o1.w};
      #pragma unroll
      for (int i=0;i<16;++i) {
        U4 wv; wv.v = *reinterpret_cast<const uint4*>(&s_wst[(lb + 8*i)*WS + 8*j]);
        float a = acc[i];
        #pragma unroll
        for (int q=0;q<4;++q){ float2 f = bf2(wv.w[q]); a += xf[2*q]*f.x + xf[2*q+1]*f.y; }
        acc[i] = a;
      }
    }
    float* dst = &out[(((long)t*H_ + (h0+py))*W_ + (w0+px))*C_];
    #pragma unroll
    for (int i=0;i<16;++i) dst[lb + 8*i] = acc[i];
  }
}

extern "C" void kernel_launch(void* const* d_in, const int* in_sizes, int n_in,
                              void* d_out, int out_size, void* d_ws, size_t ws_size,
                              hipStream_t stream) {
  const float* vid  = (const float*)d_in[0];
  const float* rpb  = (const float*)d_in[1];
  const float* qdw  = (const float*)d_in[2];
  const float* qdwb = (const float*)d_in[3];
  const float* qpw  = (const float*)d_in[4];
  const float* qpwb = (const float*)d_in[5];
  const float* kdw  = (const float*)d_in[6];
  const float* kdwb = (const float*)d_in[7];
  const float* kpw  = (const float*)d_in[8];
  const float* kpwb = (const float*)d_in[9];
  const float* vdw  = (const float*)d_in[10];
  const float* vdwb = (const float*)d_in[11];
  const float* vpw  = (const float*)d_in[12];
  const float* vpwb = (const float*)d_in[13];
  const float* pjw  = (const float*)d_in[14];
  const float* pjb  = (const float*)d_in[15];
  float* outp = (float*)d_out;

  winattn_kernel<<<dim3(NWIN_), dim3(512), 0, stream>>>(
      vid, rpb, qdw, qdwb, qpw, qpwb, kdw, kdwb, kpw, kpwb,
      vdw, vdwb, vpw, vpwb, pjw, pjb, outp);
}

// Round 2
// 350.048 us; speedup vs baseline: 5.9877x; 5.9877x over previous
//
#include <hip/hip_runtime.h>
#include <stdint.h>

#define T_ 2
#define H_ 384
#define W_ 384
#define C_ 128
#define HN_ 48
#define WN_ 48
#define NWIN_ (T_*HN_*WN_)
#define SCALE_ 0.17677669529663687f

typedef float f32x4 __attribute__((ext_vector_type(4)));
typedef short bf16x8 __attribute__((ext_vector_type(8)));

// LDS layout (bytes). Row strides padded: 136 bf16 (=272B) for 128-wide rows,
// 72 bf16 (=144B) for 64-wide rows -> column-wise b128 frag reads are max
// 2-way bank-aliased (free).
#define TMP_OFF   0        // tmp3 bf16 [3][64][136] = 52,224 ; s_O overlays tmp3[0]
#define W_OFF     52224    // s_w bf16 [128][136] = 34,816 ; s_P overlays [256][72] = 36,864
#define Q_OFF     89088    // s_q bf16 [64][136]
#define K_OFF     106496   // s_k bf16 [64][136]
#define VT_OFF    123904   // s_vt bf16 [128][72] = 18,432  (V transposed)
#define RPB_OFF   142336   // f32 [900]
#define SMEM_SZ   145936

__device__ __forceinline__ unsigned short f2bf(float f){
  union{float f;unsigned int i;}x; x.f=f;
  unsigned int r = x.i + 0x7fffu + ((x.i>>16)&1u);   // RNE
  return (unsigned short)(r>>16);
}

__global__ __launch_bounds__(512)
void winattn_mfma(const float* __restrict__ vid, const float* __restrict__ rpb,
                  const float* __restrict__ qdw, const float* __restrict__ qdwb,
                  const float* __restrict__ qpw, const float* __restrict__ qpwb,
                  const float* __restrict__ kdw, const float* __restrict__ kdwb,
                  const float* __restrict__ kpw, const float* __restrict__ kpwb,
                  const float* __restrict__ vdw, const float* __restrict__ vdwb,
                  const float* __restrict__ vpw, const float* __restrict__ vpwb,
                  const float* __restrict__ pjw, const float* __restrict__ pjb,
                  float* __restrict__ out)
{
  __shared__ __attribute__((aligned(16))) char smem[SMEM_SZ];
  ushort* s_tmp = (ushort*)(smem + TMP_OFF);
  ushort* s_O   = (ushort*)(smem + TMP_OFF);
  ushort* s_w   = (ushort*)(smem + W_OFF);
  ushort* s_P   = (ushort*)(smem + W_OFF);
  ushort* s_q   = (ushort*)(smem + Q_OFF);
  ushort* s_k   = (ushort*)(smem + K_OFF);
  ushort* s_vt  = (ushort*)(smem + VT_OFF);
  float*  s_rpb = (float*)(smem + RPB_OFF);

  const int tid  = threadIdx.x;
  const int w    = tid >> 6;        // wave 0..7
  const int lane = tid & 63;
  const int g    = lane >> 4;       // 0..3
  const int c16  = lane & 15;       // 0..15

  const int wid = blockIdx.x;
  const int t  = wid / (HN_*WN_);
  const int hw = wid % (HN_*WN_);
  const int hn = hw / WN_, wn = hw % WN_;
  const int h0 = hn*8, w0 = wn*8;

  for (int i = tid; i < 900; i += 512) s_rpb[i] = rpb[i];

  // ---- input halo -> registers. wave = output row y; lane = channel pair ----
  const int y  = w;
  const int cp = lane;              // channels 2cp, 2cp+1
  float2 xv[3][10];
  #pragma unroll
  for (int dy = 0; dy < 3; ++dy){
    const int hh = h0 + y - 1 + dy;
    const bool rv = (unsigned)hh < (unsigned)H_;
    #pragma unroll
    for (int xc = 0; xc < 10; ++xc){
      const int ww = w0 - 1 + xc;
      float2 v = make_float2(0.f, 0.f);
      if (rv && (unsigned)ww < (unsigned)W_)
        v = *reinterpret_cast<const float2*>(&vid[(((long)t*H_ + hh)*W_ + ww)*C_ + 2*cp]);
      xv[dy][xc] = v;
    }
  }

  const float* DW[3]  = {qdw, kdw, vdw};
  const float* DWB[3] = {qdwb, kdwb, vdwb};
  const float* PW[3]  = {qpw, kpw, vpw};
  const float* PWB[3] = {qpwb, kpwb, vpwb};

  const int mt  = w & 3;            // GEMM M-tile for this wave
  const int ntb = (w >> 2) * 4;     // GEMM N-tile base (0 or 4)

  for (int p = 0; p < 3; ++p) {
    // ---- depthwise 3x3 + bias + relu (from regs) -> tmp3[p] ----
    {
      const int c0 = 2*cp;
      const float* dwp = DW[p] + (long)c0*9;
      float wA[9], wB[9];
      #pragma unroll
      for (int k2 = 0; k2 < 9; ++k2){ wA[k2]=dwp[k2]; wB[k2]=dwp[9+k2]; }
      const float bA = DWB[p][c0], bB = DWB[p][c0+1];
      ushort* dst = s_tmp + p*(64*136);
      #pragma unroll
      for (int px = 0; px < 8; ++px){
        float aA = bA, aB = bB;
        #pragma unroll
        for (int dy = 0; dy < 3; ++dy)
          #pragma unroll
          for (int dx = 0; dx < 3; ++dx){
            const float2 xx = xv[dy][px+dx];
            aA += xx.x * wA[dy*3+dx];
            aB += xx.y * wB[dy*3+dx];
          }
        aA = fmaxf(aA, 0.f); aB = fmaxf(aB, 0.f);
        const unsigned int pk = (unsigned int)f2bf(aA) | ((unsigned int)f2bf(aB) << 16);
        *reinterpret_cast<unsigned int*>(&dst[(y*8+px)*136 + c0]) = pk;
      }
    }
    // ---- stage pointwise W_p -> s_w (bf16) ----
    for (int i = tid; i < 128*32; i += 512) {
      const int co = i >> 5, c4 = (i & 31) << 2;
      const float4 v = *reinterpret_cast<const float4*>(&PW[p][co*128 + c4]);
      ushort4 pk = { f2bf(v.x), f2bf(v.y), f2bf(v.z), f2bf(v.w) };
      *reinterpret_cast<ushort4*>(&s_w[co*136 + c4]) = pk;
    }
    __syncthreads();
    // ---- pointwise 1x1 GEMM: Y[64,128] = X[64,128] @ W^T, MFMA ----
    {
      const ushort* xs = s_tmp + p*(64*136);
      f32x4 acc[4];
      #pragma unroll
      for (int nt = 0; nt < 4; ++nt) acc[nt] = (f32x4){0.f,0.f,0.f,0.f};
      #pragma unroll
      for (int ks = 0; ks < 4; ++ks){
        const bf16x8 af = *reinterpret_cast<const bf16x8*>(&xs[(mt*16+c16)*136 + ks*32 + g*8]);
        #pragma unroll
        for (int nt = 0; nt < 4; ++nt){
          const bf16x8 bf = *reinterpret_cast<const bf16x8*>(&s_w[((ntb+nt)*16+c16)*136 + ks*32 + g*8]);
          acc[nt] = __builtin_amdgcn_mfma_f32_16x16x32_bf16(af, bf, acc[nt], 0, 0, 0);
        }
      }
      const float scl = (p == 0) ? SCALE_ : 1.0f;
      ushort* dq = (p == 0) ? s_q : s_k;
      #pragma unroll
      for (int nt = 0; nt < 4; ++nt){
        const int co = (ntb+nt)*16 + c16;
        const float bias = PWB[p][co];
        #pragma unroll
        for (int r = 0; r < 4; ++r){
          const int n = mt*16 + g*4 + r;
          const float val = (acc[nt][r] + bias) * scl;
          if (p < 2) dq[n*136 + co]  = f2bf(val);   // Q (scaled) / K row-major
          else       s_vt[co*72 + n] = f2bf(val);   // V transposed [d][n]
        }
      }
    }
    __syncthreads();
  }

  // ---- attention: wave (he, half) owns 32 query rows of head he ----
  const int he = w >> 1, half = w & 1;
  {
    // QK^T: S[n,m], A=Q rows, B=K rows (B^T GEMM), K=32 -> 1 MFMA/tile
    f32x4 S[2][4];
    #pragma unroll
    for (int mi = 0; mi < 2; ++mi){
      const bf16x8 qf = *reinterpret_cast<const bf16x8*>(&s_q[((half*2+mi)*16+c16)*136 + he*32 + g*8]);
      #pragma unroll
      for (int m2 = 0; m2 < 4; ++m2){
        const bf16x8 kf = *reinterpret_cast<const bf16x8*>(&s_k[(m2*16+c16)*136 + he*32 + g*8]);
        const f32x4 z = {0.f,0.f,0.f,0.f};
        S[mi][m2] = __builtin_amdgcn_mfma_f32_16x16x32_bf16(qf, kf, z, 0, 0, 0);
      }
    }
    // bias + exact row softmax on fragment layout (row n = g*4+r, col m = m2*16+c16)
    #pragma unroll
    for (int mi = 0; mi < 2; ++mi){
      #pragma unroll
      for (int r = 0; r < 4; ++r){
        const int n = (half*2+mi)*16 + g*4 + r;
        const int ny = n >> 3, nx = n & 7;
        float v0[4];
        #pragma unroll
        for (int m2 = 0; m2 < 4; ++m2){
          const int m = m2*16 + c16;
          v0[m2] = S[mi][m2][r] + s_rpb[((ny-(m>>3)+7)*15 + (nx-(m&7)+7))*4 + he];
        }
        float mx = fmaxf(fmaxf(v0[0],v0[1]), fmaxf(v0[2],v0[3]));
        mx = fmaxf(mx, __shfl_xor(mx, 1));
        mx = fmaxf(mx, __shfl_xor(mx, 2));
        mx = fmaxf(mx, __shfl_xor(mx, 4));
        mx = fmaxf(mx, __shfl_xor(mx, 8));
        const float e0 = __expf(v0[0]-mx), e1 = __expf(v0[1]-mx);
        const float e2 = __expf(v0[2]-mx), e3 = __expf(v0[3]-mx);
        float ls = e0+e1+e2+e3;
        ls += __shfl_xor(ls, 1);
        ls += __shfl_xor(ls, 2);
        ls += __shfl_xor(ls, 4);
        ls += __shfl_xor(ls, 8);
        const float inv = 1.0f / ls;
        ushort* pr = &s_P[(he*64+n)*72 + c16];
        pr[0]  = f2bf(e0*inv);
        pr[16] = f2bf(e1*inv);
        pr[32] = f2bf(e2*inv);
        pr[48] = f2bf(e3*inv);
      }
    }
  }
  __syncthreads();
  // ---- PV: O[n,d] = P[64,64] @ V[64,32] per head (B from s_vt, contiguous) ----
  {
    f32x4 oacc[2][2];
    #pragma unroll
    for (int mi = 0; mi < 2; ++mi)
      #pragma unroll
      for (int nt = 0; nt < 2; ++nt) oacc[mi][nt] = (f32x4){0.f,0.f,0.f,0.f};
    #pragma unroll
    for (int ks = 0; ks < 2; ++ks){
      #pragma unroll
      for (int nt = 0; nt < 2; ++nt){
        const bf16x8 vf = *reinterpret_cast<const bf16x8*>(&s_vt[(he*32+nt*16+c16)*72 + ks*32 + g*8]);
        #pragma unroll
        for (int mi = 0; mi < 2; ++mi){
          const bf16x8 pf = *reinterpret_cast<const bf16x8*>(&s_P[(he*64+(half*2+mi)*16+c16)*72 + ks*32 + g*8]);
          oacc[mi][nt] = __builtin_amdgcn_mfma_f32_16x16x32_bf16(pf, vf, oacc[mi][nt], 0, 0, 0);
        }
      }
    }
    #pragma unroll
    for (int mi = 0; mi < 2; ++mi)
      #pragma unroll
      for (int nt = 0; nt < 2; ++nt)
        #pragma unroll
        for (int r = 0; r < 4; ++r){
          const int n = (half*2+mi)*16 + g*4 + r;
          s_O[n*136 + he*32 + nt*16 + c16] = f2bf(oacc[mi][nt][r]);  // merged heads
        }
  }
  __syncthreads();
  // ---- stage proj W -> s_w (overwrites s_P, guarded by barrier) ----
  for (int i = tid; i < 128*32; i += 512) {
    const int co = i >> 5, c4 = (i & 31) << 2;
    const float4 v = *reinterpret_cast<const float4*>(&pjw[co*128 + c4]);
    ushort4 pk = { f2bf(v.x), f2bf(v.y), f2bf(v.z), f2bf(v.w) };
    *reinterpret_cast<ushort4*>(&s_w[co*136 + c4]) = pk;
  }
  __syncthreads();
  // ---- projection GEMM + coalesced fp32 output ----
  {
    f32x4 acc[4];
    #pragma unroll
    for (int nt = 0; nt < 4; ++nt) acc[nt] = (f32x4){0.f,0.f,0.f,0.f};
    #pragma unroll
    for (int ks = 0; ks < 4; ++ks){
      const bf16x8 af = *reinterpret_cast<const bf16x8*>(&s_O[(mt*16+c16)*136 + ks*32 + g*8]);
      #pragma unroll
      for (int nt = 0; nt < 4; ++nt){
        const bf16x8 bf = *reinterpret_cast<const bf16x8*>(&s_w[((ntb+nt)*16+c16)*136 + ks*32 + g*8]);
        acc[nt] = __builtin_amdgcn_mfma_f32_16x16x32_bf16(af, bf, acc[nt], 0, 0, 0);
      }
    }
    #pragma unroll
    for (int nt = 0; nt < 4; ++nt){
      const int co = (ntb+nt)*16 + c16;
      const float bias = pjb[co];
      #pragma unroll
      for (int r = 0; r < 4; ++r){
        const int n = mt*16 + g*4 + r;
        const int py2 = n >> 3, px2 = n & 7;
        out[(((long)t*H_ + (h0+py2))*W_ + (w0+px2))*C_ + co] = acc[nt][r] + bias;
      }
    }
  }
}

extern "C" void kernel_launch(void* const* d_in, const int* in_sizes, int n_in,
                              void* d_out, int out_size, void* d_ws, size_t ws_size,
                              hipStream_t stream) {
  const float* vid  = (const float*)d_in[0];
  const float* rpb  = (const float*)d_in[1];
  const float* qdw  = (const float*)d_in[2];
  const float* qdwb = (const float*)d_in[3];
  const float* qpw  = (const float*)d_in[4];
  const float* qpwb = (const float*)d_in[5];
  const float* kdw  = (const float*)d_in[6];
  const float* kdwb = (const float*)d_in[7];
  const float* kpw  = (const float*)d_in[8];
  const float* kpwb = (const float*)d_in[9];
  const float* vdw  = (const float*)d_in[10];
  const float* vdwb = (const float*)d_in[11];
  const float* vpw  = (const float*)d_in[12];
  const float* vpwb = (const float*)d_in[13];
  const float* pjw  = (const float*)d_in[14];
  const float* pjb  = (const float*)d_in[15];
  float* outp = (float*)d_out;

  winattn_mfma<<<dim3(NWIN_), dim3(512), 0, stream>>>(
      vid, rpb, qdw, qdwb, qpw, qpwb, kdw, kdwb, kpw, kpwb,
      vdw, vdwb, vpw, vpwb, pjw, pjb, outp);
}

// Round 3
// 326.756 us; speedup vs baseline: 6.4145x; 1.0713x over previous
//
#include <hip/hip_runtime.h>
#include <stdint.h>

#define T_ 2
#define H_ 384
#define W_ 384
#define C_ 128
#define HN_ 48
#define WN_ 48
#define NWIN_ (T_*HN_*WN_)
#define SCALE_ 0.17677669529663687f

typedef float f32x4 __attribute__((ext_vector_type(4)));
typedef short bf16x8 __attribute__((ext_vector_type(8)));

// ---- workspace layout (bytes) ----
// wfrag: 4 mats x [nt8=8][ks=4][lane=64][8] bf16  = 4*32KB = 131072
// biasx: [he=4][n=64][c16=16][m2=4] f32           = 65536
#define WS_WFRAG 0
#define WS_BIASX 131072

// ---- LDS layout ----
// s_tmp [64][136] bf16 = 17408   (overlay: s_O)
// s_q   [64][136] bf16 = 17408   (overlay: s_P [256][68] spans q+k exactly)
// s_k   [64][136] bf16 = 17408
// s_vt  [128][72] bf16 = 18432
#define TMP_OFF 0
#define Q_OFF   17408
#define K_OFF   34816
#define VT_OFF  52224
#define SMEM_SZ 70656

__device__ __forceinline__ unsigned short f2bf(float f){
  union{float f;unsigned int i;}x; x.f=f;
  unsigned int r = x.i + 0x7fffu + ((x.i>>16)&1u);   // RNE
  return (unsigned short)(r>>16);
}

// ---------- prep: weights -> bf16 fragment order; rpb -> expanded fragment bias ----------
__global__ __launch_bounds__(256)
void prep_kernel(const float* __restrict__ qpw, const float* __restrict__ kpw,
                 const float* __restrict__ vpw, const float* __restrict__ pjw,
                 const float* __restrict__ rpb, ushort* __restrict__ wfrag,
                 float* __restrict__ biasx)
{
  const int idx = blockIdx.x*256 + threadIdx.x;
  if (idx < 8192) {            // weight fragment units: [mat][nt8][ks][lane] of 8 values
    const int mat = idx >> 11, rem = idx & 2047;
    const int nt8 = rem >> 8, ks = (rem >> 6) & 3, lane = rem & 63;
    const int c16 = lane & 15, g = lane >> 4;
    const float* Ws[4] = {qpw, kpw, vpw, pjw};
    const float* src = Ws[mat] + (nt8*16 + c16)*128 + ks*32 + g*8;
    ushort* dst = wfrag + idx*8;
    #pragma unroll
    for (int e = 0; e < 8; ++e) dst[e] = f2bf(src[e]);
  } else if (idx < 8192 + 16384) {  // bias expand: (he,n,m) -> [he][n][m&15][m>>4]
    const int i2 = idx - 8192;
    const int he = i2 >> 12, n = (i2 >> 6) & 63, m = i2 & 63;
    const int ny = n >> 3, nx = n & 7, my = m >> 3, mx = m & 7;
    biasx[((he*64 + n)*16 + (m & 15))*4 + (m >> 4)] =
        rpb[((ny - my + 7)*15 + (nx - mx + 7))*4 + he];
  }
}

// ---------- main ----------
__global__ __launch_bounds__(512, 4)
void winattn_mfma2(const float* __restrict__ vid,
                   const float* __restrict__ qdw, const float* __restrict__ qdwb,
                   const float* __restrict__ kdw, const float* __restrict__ kdwb,
                   const float* __restrict__ vdw, const float* __restrict__ vdwb,
                   const float* __restrict__ qpwb, const float* __restrict__ kpwb,
                   const float* __restrict__ vpwb, const float* __restrict__ pjb,
                   const ushort* __restrict__ wfrag, const float* __restrict__ biasx,
                   float* __restrict__ out)
{
  __shared__ __attribute__((aligned(16))) char smem[SMEM_SZ];
  ushort* s_tmp = (ushort*)(smem + TMP_OFF);
  ushort* s_O   = (ushort*)(smem + TMP_OFF);
  ushort* s_q   = (ushort*)(smem + Q_OFF);
  ushort* s_P   = (ushort*)(smem + Q_OFF);   // [256][68] overlays q+k
  ushort* s_k   = (ushort*)(smem + K_OFF);
  ushort* s_vt  = (ushort*)(smem + VT_OFF);

  const int tid  = threadIdx.x;
  const int w    = tid >> 6;
  const int lane = tid & 63;
  const int g    = lane >> 4;
  const int c16  = lane & 15;

  const int wid = blockIdx.x;
  const int t  = wid / (HN_*WN_);
  const int hw = wid % (HN_*WN_);
  const int hn = hw / WN_, wn = hw % WN_;
  const int h0 = hn*8, w0 = wn*8;

  // ---- input halo -> registers (wave = row y, lane = channel pair) ----
  const int y  = w;
  float2 xv[3][10];
  #pragma unroll
  for (int dy = 0; dy < 3; ++dy){
    const int hh = h0 + y - 1 + dy;
    const bool rv = (unsigned)hh < (unsigned)H_;
    #pragma unroll
    for (int xc = 0; xc < 10; ++xc){
      const int ww = w0 - 1 + xc;
      float2 v = make_float2(0.f, 0.f);
      if (rv && (unsigned)ww < (unsigned)W_)
        v = *reinterpret_cast<const float2*>(&vid[(((long)t*H_ + hh)*W_ + ww)*C_ + 2*lane]);
      xv[dy][xc] = v;
    }
  }

  const float* DW[3]  = {qdw, kdw, vdw};
  const float* DWB[3] = {qdwb, kdwb, vdwb};
  const float* PWB[3] = {qpwb, kpwb, vpwb};

  const int mt  = w & 3;
  const int ntb = (w >> 2) * 4;

  for (int p = 0; p < 3; ++p) {
    // ---- depthwise 3x3 + bias + relu (regs) -> s_tmp ----
    {
      const int c0 = 2*lane;
      const float* dwp = DW[p] + (long)c0*9;
      float wA[9], wB[9];
      #pragma unroll
      for (int k2 = 0; k2 < 9; ++k2){ wA[k2]=dwp[k2]; wB[k2]=dwp[9+k2]; }
      const float bA = DWB[p][c0], bB = DWB[p][c0+1];
      #pragma unroll
      for (int px = 0; px < 8; ++px){
        float aA = bA, aB = bB;
        #pragma unroll
        for (int dy = 0; dy < 3; ++dy)
          #pragma unroll
          for (int dx = 0; dx < 3; ++dx){
            const float2 xx = xv[dy][px+dx];
            aA += xx.x * wA[dy*3+dx];
            aB += xx.y * wB[dy*3+dx];
          }
        aA = fmaxf(aA, 0.f); aB = fmaxf(aB, 0.f);
        const unsigned int pk = (unsigned int)f2bf(aA) | ((unsigned int)f2bf(aB) << 16);
        *reinterpret_cast<unsigned int*>(&s_tmp[(y*8+px)*136 + c0]) = pk;
      }
    }
    __syncthreads();
    // ---- pointwise GEMM: Y[64,128] = X @ W^T ; B-fragments direct from L2 ----
    {
      const ushort* wp = wfrag + p*16384;
      f32x4 acc[4];
      #pragma unroll
      for (int nt = 0; nt < 4; ++nt) acc[nt] = (f32x4){0.f,0.f,0.f,0.f};
      #pragma unroll
      for (int ks = 0; ks < 4; ++ks){
        const bf16x8 af = *reinterpret_cast<const bf16x8*>(&s_tmp[(mt*16+c16)*136 + ks*32 + g*8]);
        #pragma unroll
        for (int nt = 0; nt < 4; ++nt){
          const bf16x8 bf = *reinterpret_cast<const bf16x8*>(&wp[(((ntb+nt)*4 + ks)*64 + lane)*8]);
          acc[nt] = __builtin_amdgcn_mfma_f32_16x16x32_bf16(af, bf, acc[nt], 0, 0, 0);
        }
      }
      const float scl = (p == 0) ? SCALE_ : 1.0f;
      ushort* dq = (p == 0) ? s_q : s_k;
      #pragma unroll
      for (int nt = 0; nt < 4; ++nt){
        const int co = (ntb+nt)*16 + c16;
        const float bias = PWB[p][co];
        #pragma unroll
        for (int r = 0; r < 4; ++r){
          const int n = mt*16 + g*4 + r;
          const float val = (acc[nt][r] + bias) * scl;
          if (p < 2) dq[n*136 + co]  = f2bf(val);
          else       s_vt[co*72 + n] = f2bf(val);
        }
      }
    }
    __syncthreads();
  }

  // ---- attention: wave (he, half) owns 32 query rows ----
  const int he = w >> 1, half = w & 1;
  float pv[2][16];  // normalized P values (register escrow while barriers pass)
  {
    f32x4 S[2][4];
    #pragma unroll
    for (int mi = 0; mi < 2; ++mi){
      const bf16x8 qf = *reinterpret_cast<const bf16x8*>(&s_q[((half*2+mi)*16+c16)*136 + he*32 + g*8]);
      #pragma unroll
      for (int m2 = 0; m2 < 4; ++m2){
        const bf16x8 kf = *reinterpret_cast<const bf16x8*>(&s_k[(m2*16+c16)*136 + he*32 + g*8]);
        const f32x4 z = {0.f,0.f,0.f,0.f};
        S[mi][m2] = __builtin_amdgcn_mfma_f32_16x16x32_bf16(qf, kf, z, 0, 0, 0);
      }
    }
    #pragma unroll
    for (int mi = 0; mi < 2; ++mi){
      #pragma unroll
      for (int r = 0; r < 4; ++r){
        const int n = (half*2+mi)*16 + g*4 + r;
        const float4 bx = *reinterpret_cast<const float4*>(&biasx[((he*64+n)*16 + c16)*4]);
        float v0[4] = { S[mi][0][r]+bx.x, S[mi][1][r]+bx.y, S[mi][2][r]+bx.z, S[mi][3][r]+bx.w };
        float mx = fmaxf(fmaxf(v0[0],v0[1]), fmaxf(v0[2],v0[3]));
        mx = fmaxf(mx, __shfl_xor(mx, 1));
        mx = fmaxf(mx, __shfl_xor(mx, 2));
        mx = fmaxf(mx, __shfl_xor(mx, 4));
        mx = fmaxf(mx, __shfl_xor(mx, 8));
        const float e0 = __expf(v0[0]-mx), e1 = __expf(v0[1]-mx);
        const float e2 = __expf(v0[2]-mx), e3 = __expf(v0[3]-mx);
        float ls = e0+e1+e2+e3;
        ls += __shfl_xor(ls, 1);
        ls += __shfl_xor(ls, 2);
        ls += __shfl_xor(ls, 4);
        ls += __shfl_xor(ls, 8);
        const float inv = 1.0f / ls;
        pv[mi][r*4+0] = e0*inv; pv[mi][r*4+1] = e1*inv;
        pv[mi][r*4+2] = e2*inv; pv[mi][r*4+3] = e3*inv;
      }
    }
  }
  __syncthreads();                       // all QK^T reads of s_q/s_k done
  #pragma unroll
  for (int mi = 0; mi < 2; ++mi)
    #pragma unroll
    for (int r = 0; r < 4; ++r){
      const int n = (half*2+mi)*16 + g*4 + r;
      ushort* pr = &s_P[(he*64+n)*68 + c16];
      pr[0]  = f2bf(pv[mi][r*4+0]);
      pr[16] = f2bf(pv[mi][r*4+1]);
      pr[32] = f2bf(pv[mi][r*4+2]);
      pr[48] = f2bf(pv[mi][r*4+3]);
    }
  __syncthreads();
  // ---- PV: O = P @ V  (B from s_vt) ----
  {
    f32x4 oacc[2][2];
    #pragma unroll
    for (int mi = 0; mi < 2; ++mi)
      #pragma unroll
      for (int nt = 0; nt < 2; ++nt) oacc[mi][nt] = (f32x4){0.f,0.f,0.f,0.f};
    #pragma unroll
    for (int ks = 0; ks < 2; ++ks){
      #pragma unroll
      for (int nt = 0; nt < 2; ++nt){
        const bf16x8 vf = *reinterpret_cast<const bf16x8*>(&s_vt[(he*32+nt*16+c16)*72 + ks*32 + g*8]);
        #pragma unroll
        for (int mi = 0; mi < 2; ++mi){
          const bf16x8 pf = *reinterpret_cast<const bf16x8*>(&s_P[(he*64+(half*2+mi)*16+c16)*68 + ks*32 + g*8]);
          oacc[mi][nt] = __builtin_amdgcn_mfma_f32_16x16x32_bf16(pf, vf, oacc[mi][nt], 0, 0, 0);
        }
      }
    }
    #pragma unroll
    for (int mi = 0; mi < 2; ++mi)
      #pragma unroll
      for (int nt = 0; nt < 2; ++nt)
        #pragma unroll
        for (int r = 0; r < 4; ++r){
          const int n = (half*2+mi)*16 + g*4 + r;
          s_O[n*136 + he*32 + nt*16 + c16] = f2bf(oacc[mi][nt][r]);
        }
  }
  __syncthreads();
  // ---- projection GEMM (B-fragments from L2) + output ----
  {
    const ushort* wp = wfrag + 3*16384;
    f32x4 acc[4];
    #pragma unroll
    for (int nt = 0; nt < 4; ++nt) acc[nt] = (f32x4){0.f,0.f,0.f,0.f};
    #pragma unroll
    for (int ks = 0; ks < 4; ++ks){
      const bf16x8 af = *reinterpret_cast<const bf16x8*>(&s_O[(mt*16+c16)*136 + ks*32 + g*8]);
      #pragma unroll
      for (int nt = 0; nt < 4; ++nt){
        const bf16x8 bf = *reinterpret_cast<const bf16x8*>(&wp[(((ntb+nt)*4 + ks)*64 + lane)*8]);
        acc[nt] = __builtin_amdgcn_mfma_f32_16x16x32_bf16(af, bf, acc[nt], 0, 0, 0);
      }
    }
    #pragma unroll
    for (int nt = 0; nt < 4; ++nt){
      const int co = (ntb+nt)*16 + c16;
      const float bias = pjb[co];
      #pragma unroll
      for (int r = 0; r < 4; ++r){
        const int n = mt*16 + g*4 + r;
        out[(((long)t*H_ + (h0+(n>>3)))*W_ + (w0+(n&7)))*C_ + co] = acc[nt][r] + bias;
      }
    }
  }
}

extern "C" void kernel_launch(void* const* d_in, const int* in_sizes, int n_in,
                              void* d_out, int out_size, void* d_ws, size_t ws_size,
                              hipStream_t stream) {
  const float* vid  = (const float*)d_in[0];
  const float* rpb  = (const float*)d_in[1];
  const float* qdw  = (const float*)d_in[2];
  const float* qdwb = (const float*)d_in[3];
  const float* qpw  = (const float*)d_in[4];
  const float* qpwb = (const float*)d_in[5];
  const float* kdw  = (const float*)d_in[6];
  const float* kdwb = (const float*)d_in[7];
  const float* kpw  = (const float*)d_in[8];
  const float* kpwb = (const float*)d_in[9];
  const float* vdw  = (const float*)d_in[10];
  const float* vdwb = (const float*)d_in[11];
  const float* vpw  = (const float*)d_in[12];
  const float* vpwb = (const float*)d_in[13];
  const float* pjw  = (const float*)d_in[14];
  const float* pjb  = (const float*)d_in[15];
  float* outp = (float*)d_out;

  ushort* wfrag = (ushort*)((char*)d_ws + WS_WFRAG);
  float*  biasx = (float*)((char*)d_ws + WS_BIASX);

  prep_kernel<<<dim3(96), dim3(256), 0, stream>>>(qpw, kpw, vpw, pjw, rpb, wfrag, biasx);
  winattn_mfma2<<<dim3(NWIN_), dim3(512), 0, stream>>>(
      vid, qdw, qdwb, kdw, kdwb, vdw, vdwb, qpwb, kpwb, vpwb, pjb,
      wfrag, biasx, outp);
}